// Round 1
// baseline (609.626 us; speedup 1.0000x reference)
//
#include <hip/hip_runtime.h>

typedef short short8 __attribute__((ext_vector_type(8)));
typedef float f32x4 __attribute__((ext_vector_type(4)));

__device__ __forceinline__ unsigned short f2bf(float f) {
    unsigned int u = __float_as_uint(f);
    u += 0x7FFFu + ((u >> 16) & 1u);   // RNE; inputs are finite/tame, no NaN path
    return (unsigned short)(u >> 16);
}
__device__ __forceinline__ float bf2f(unsigned short s) {
    return __uint_as_float(((unsigned int)s) << 16);
}

// ---------------- CSR build ----------------

__global__ void count_k(const int* __restrict__ ei, int* __restrict__ cnt, int E) {
    int e = blockIdx.x * 256 + threadIdx.x;
    if (e < E) atomicAdd(&cnt[ei[E + e]], 1);   // dst row of edge_index
}

__global__ __launch_bounds__(1024) void reduce_k(const int* __restrict__ cnt,
                                                 int* __restrict__ bsum, int N) {
    __shared__ int s[1024];
    int i = blockIdx.x * 1024 + threadIdx.x;
    int v = (i < N) ? cnt[i] : 0;
    s[threadIdx.x] = v;
    __syncthreads();
    for (int o = 512; o; o >>= 1) {
        if (threadIdx.x < o) s[threadIdx.x] += s[threadIdx.x + o];
        __syncthreads();
    }
    if (threadIdx.x == 0) bsum[blockIdx.x] = s[0];
}

__global__ __launch_bounds__(256) void scantop_k(const int* __restrict__ bsum,
                                                 int* __restrict__ boff, int NB) {
    __shared__ int s[256];
    int v = (threadIdx.x < NB) ? bsum[threadIdx.x] : 0;
    s[threadIdx.x] = v;
    __syncthreads();
    for (int o = 1; o < 256; o <<= 1) {
        int t = (threadIdx.x >= o) ? s[threadIdx.x - o] : 0;
        __syncthreads();
        s[threadIdx.x] += t;
        __syncthreads();
    }
    if (threadIdx.x < NB) boff[threadIdx.x] = s[threadIdx.x] - v;  // exclusive
}

__global__ __launch_bounds__(1024) void scanblk_k(const int* __restrict__ cnt,
                                                  const int* __restrict__ boff,
                                                  int* __restrict__ rowoff,
                                                  int* __restrict__ cursor,
                                                  float* __restrict__ inv, int N) {
    __shared__ int s[1024];
    int i = blockIdx.x * 1024 + threadIdx.x;
    int v = (i < N) ? cnt[i] : 0;
    s[threadIdx.x] = v;
    __syncthreads();
    for (int o = 1; o < 1024; o <<= 1) {
        int t = (threadIdx.x >= o) ? s[threadIdx.x - o] : 0;
        __syncthreads();
        s[threadIdx.x] += t;
        __syncthreads();
    }
    int ex = s[threadIdx.x] - v + boff[blockIdx.x];
    if (i < N) {
        rowoff[i] = ex;
        cursor[i] = ex;
        inv[i] = 1.0f / (float)max(v, 1);
        if (i == N - 1) rowoff[N] = ex + v;   // == E
    }
}

__global__ void fill_k(const int* __restrict__ ei, int* __restrict__ cursor,
                       int* __restrict__ col, int E) {
    int e = blockIdx.x * 256 + threadIdx.x;
    if (e < E) {
        int pos = atomicAdd(&cursor[ei[E + e]], 1);
        col[pos] = ei[e];   // src
    }
}

// ---------------- dtype prep ----------------

__global__ void cvt_x_k(const float* __restrict__ x, unsigned short* __restrict__ xb,
                        int total4) {
    int i = blockIdx.x * 256 + threadIdx.x;
    if (i < total4) {
        float4 v = ((const float4*)x)[i];
        ushort4 p;
        p.x = f2bf(v.x); p.y = f2bf(v.y); p.z = f2bf(v.z); p.w = f2bf(v.w);
        ((ushort4*)xb)[i] = p;
    }
}

// Convert 4 weight matrices (f32 [128][128] row-major, W[k][n]) into bf16
// pre-swizzled B-fragment layout for mfma_f32_16x16x32_bf16:
//   B frag: lane l holds B[k = ktile*32 + (l>>4)*8 + j][n = ctile*16 + (l&15)], j=0..7
//   stored at ((ktile*8 + ctile)*64 + l)*8 + j  → GEMM does contiguous ds_read_b128
__global__ void cvt_w_k(const float* __restrict__ W0, const float* __restrict__ W1,
                        const float* __restrict__ W2, const float* __restrict__ W3,
                        unsigned short* __restrict__ wsz) {
    int idx = blockIdx.x * 256 + threadIdx.x;
    if (idx >= 4 * 16384) return;
    int m = idx >> 14, r = idx & 16383;
    const float* W = (m == 0) ? W0 : (m == 1) ? W1 : (m == 2) ? W2 : W3;
    int k = r >> 7, n = r & 127;
    int t = k >> 5, kg = (k >> 3) & 3, j = k & 7;
    int c = n >> 4, ln = n & 15;
    int dst = (((t * 8 + c) * 64) + kg * 16 + ln) * 8 + j;
    wsz[m * 16384 + dst] = f2bf(W[r]);
}

// ---------------- aggregation: wave per node ----------------

__global__ __launch_bounds__(256) void agg_f32(const float* __restrict__ x,
                                               const int* __restrict__ rowoff,
                                               const int* __restrict__ col,
                                               const float* __restrict__ inv,
                                               unsigned short* __restrict__ mean, int N) {
    int lane = threadIdx.x & 63;
    int n = blockIdx.x * 4 + (threadIdx.x >> 6);
    if (n >= N) return;
    int beg = rowoff[n], end = rowoff[n + 1];
    float a0 = 0.f, a1 = 0.f;
    for (int j0 = beg; j0 < end; j0 += 64) {
        int m = min(end - j0, 64);
        int src0 = (lane < m) ? col[j0 + lane] : 0;
        for (int jj = 0; jj < m; jj++) {
            int s = __shfl(src0, jj);
            float2 v = *(const float2*)(x + (size_t)s * 128 + lane * 2);
            a0 += fmaxf(v.x, 0.f);
            a1 += fmaxf(v.y, 0.f);
        }
    }
    float iv = inv[n];
    a0 *= iv; a1 *= iv;
    ushort2 p; p.x = f2bf(a0); p.y = f2bf(a1);
    *(ushort2*)(mean + (size_t)n * 128 + lane * 2) = p;
}

__global__ __launch_bounds__(256) void agg_bf16(const unsigned short* __restrict__ h,
                                                const int* __restrict__ rowoff,
                                                const int* __restrict__ col,
                                                const float* __restrict__ inv,
                                                unsigned short* __restrict__ mean, int N) {
    int lane = threadIdx.x & 63;
    int n = blockIdx.x * 4 + (threadIdx.x >> 6);
    if (n >= N) return;
    int beg = rowoff[n], end = rowoff[n + 1];
    float a0 = 0.f, a1 = 0.f;
    for (int j0 = beg; j0 < end; j0 += 64) {
        int m = min(end - j0, 64);
        int src0 = (lane < m) ? col[j0 + lane] : 0;
        for (int jj = 0; jj < m; jj++) {
            int s = __shfl(src0, jj);
            unsigned int v = *(const unsigned int*)(h + (size_t)s * 128 + lane * 2);
            a0 += fmaxf(bf2f((unsigned short)(v & 0xFFFFu)), 0.f);
            a1 += fmaxf(bf2f((unsigned short)(v >> 16)), 0.f);
        }
    }
    float iv = inv[n];
    a0 *= iv; a1 *= iv;
    ushort2 p; p.x = f2bf(a0); p.y = f2bf(a1);
    *(ushort2*)(mean + (size_t)n * 128 + lane * 2) = p;
}

// ---------------- fused GEMM: out = A@Wa + Z@Wb + bias (opt relu) ----------------
// A,Z: [M,128] bf16 row-major. wsz: 2 contiguous swizzled weight mats (32KB each).
// Block = 4 waves; wave computes one 16-row tile x 128 cols via 8 col-tiles.

template <bool RELU, bool OUT_BF16>
__global__ __launch_bounds__(256) void gemm_fused(const unsigned short* __restrict__ A,
                                                  const unsigned short* __restrict__ Z,
                                                  const unsigned short* __restrict__ wsz,
                                                  const float* __restrict__ bias,
                                                  float* __restrict__ outF,
                                                  unsigned short* __restrict__ outB,
                                                  int M, int NT) {
    __shared__ unsigned short smem[32768];   // 64 KB: [0]=Wa frags, [16384]=Wb frags
    {
        const int4* src = (const int4*)wsz;
        int4* dst = (int4*)smem;
        for (int i = threadIdx.x; i < 4096; i += 256) dst[i] = src[i];
    }
    __syncthreads();

    int lane = threadIdx.x & 63;
    int wv = threadIdx.x >> 6;
    int r16 = lane & 15, kg = lane >> 4;

    for (int rt = blockIdx.x * 4 + wv; rt < NT; rt += gridDim.x * 4) {
        int rbase = rt * 16;
        int row = rbase + r16;
        short8 af[4], zf[4];
        if (row < M) {
            const short8* ap = (const short8*)(A + (size_t)row * 128);
            const short8* zp = (const short8*)(Z + (size_t)row * 128);
#pragma unroll
            for (int t = 0; t < 4; t++) { af[t] = ap[t * 4 + kg]; zf[t] = zp[t * 4 + kg]; }
        } else {
            short8 zr = {0, 0, 0, 0, 0, 0, 0, 0};
#pragma unroll
            for (int t = 0; t < 4; t++) { af[t] = zr; zf[t] = zr; }
        }
#pragma unroll
        for (int c = 0; c < 8; c++) {
            float bv = bias[c * 16 + r16];
            f32x4 acc = {bv, bv, bv, bv};
#pragma unroll
            for (int t = 0; t < 4; t++) {
                short8 wa = *(const short8*)(smem + ((t * 8 + c) * 64 + lane) * 8);
                acc = __builtin_amdgcn_mfma_f32_16x16x32_bf16(af[t], wa, acc, 0, 0, 0);
            }
#pragma unroll
            for (int t = 0; t < 4; t++) {
                short8 wb = *(const short8*)(smem + 16384 + ((t * 8 + c) * 64 + lane) * 8);
                acc = __builtin_amdgcn_mfma_f32_16x16x32_bf16(zf[t], wb, acc, 0, 0, 0);
            }
#pragma unroll
            for (int r = 0; r < 4; r++) {
                int orow = rbase + kg * 4 + r;   // C/D: row=(lane>>4)*4+reg, col=lane&15
                if (orow < M) {
                    float v = acc[r];
                    if (RELU) v = fmaxf(v, 0.f);
                    if (OUT_BF16)
                        outB[(size_t)orow * 128 + c * 16 + r16] = f2bf(v);
                    else
                        outF[(size_t)orow * 128 + c * 16 + r16] = v;
                }
            }
        }
    }
}

// ---------------- launch ----------------

extern "C" void kernel_launch(void* const* d_in, const int* in_sizes, int n_in,
                              void* d_out, int out_size, void* d_ws, size_t ws_size,
                              hipStream_t stream) {
    const float* x   = (const float*)d_in[0];
    const int*   ei  = (const int*)d_in[1];
    const float* Wl1 = (const float*)d_in[2];
    const float* bl1 = (const float*)d_in[3];
    const float* Wr1 = (const float*)d_in[4];
    const float* Wl2 = (const float*)d_in[5];
    const float* bl2 = (const float*)d_in[6];
    const float* Wr2 = (const float*)d_in[7];

    int N = in_sizes[0] / 128;
    int E = in_sizes[1] / 2;

    char* ws = (char*)d_ws;
    size_t off = 0;
    auto alloc = [&](size_t bytes) -> char* {
        char* p = ws + off;
        off += (bytes + 255) & ~(size_t)255;
        return p;
    };
    int*   cnt    = (int*)alloc((size_t)N * 4);
    int*   rowoff = (int*)alloc((size_t)(N + 1) * 4);
    int*   cursor = (int*)alloc((size_t)N * 4);
    float* inv    = (float*)alloc((size_t)N * 4);
    int*   bsum   = (int*)alloc(256 * 4);
    int*   boff   = (int*)alloc(256 * 4);
    int*   col    = (int*)alloc((size_t)E * 4);
    unsigned short* xb    = (unsigned short*)alloc((size_t)N * 128 * 2);
    unsigned short* meanB = (unsigned short*)alloc((size_t)N * 128 * 2);
    unsigned short* hb    = (unsigned short*)alloc((size_t)N * 128 * 2);
    unsigned short* wsz   = (unsigned short*)alloc(4 * 16384 * 2);

    hipMemsetAsync(cnt, 0, (size_t)N * 4, stream);

    int NB = (N + 1023) / 1024;
    count_k<<<(E + 255) / 256, 256, 0, stream>>>(ei, cnt, E);
    reduce_k<<<NB, 1024, 0, stream>>>(cnt, bsum, N);
    scantop_k<<<1, 256, 0, stream>>>(bsum, boff, NB);
    scanblk_k<<<NB, 1024, 0, stream>>>(cnt, boff, rowoff, cursor, inv, N);
    fill_k<<<(E + 255) / 256, 256, 0, stream>>>(ei, cursor, col, E);

    cvt_x_k<<<(N * 128 / 4 + 255) / 256, 256, 0, stream>>>(x, xb, N * 128 / 4);
    cvt_w_k<<<(4 * 16384 + 255) / 256, 256, 0, stream>>>(Wl1, Wr1, Wl2, Wr2, wsz);

    int NT = (N + 15) / 16;
    // layer 1
    agg_f32<<<(N + 3) / 4, 256, 0, stream>>>(x, rowoff, col, inv, meanB, N);
    gemm_fused<true, true><<<512, 256, 0, stream>>>(meanB, xb, wsz, bl1, nullptr, hb, N, NT);
    // layer 2 (meanB safely reused after gemm1 completes)
    agg_bf16<<<(N + 3) / 4, 256, 0, stream>>>(hb, rowoff, col, inv, meanB, N);
    gemm_fused<false, false><<<512, 256, 0, stream>>>(meanB, hb, wsz + 32768, bl2,
                                                      (float*)d_out, nullptr, N, NT);
}

// Round 2
// 529.570 us; speedup vs baseline: 1.1512x; 1.1512x over previous
//
#include <hip/hip_runtime.h>

typedef short short8 __attribute__((ext_vector_type(8)));
typedef float f32x4 __attribute__((ext_vector_type(4)));

__device__ __forceinline__ unsigned short f2bf(float f) {
    unsigned int u = __float_as_uint(f);
    u += 0x7FFFu + ((u >> 16) & 1u);   // RNE
    return (unsigned short)(u >> 16);
}
__device__ __forceinline__ float bf2f(unsigned short s) {
    return __uint_as_float(((unsigned int)s) << 16);
}

// ---------------- CSR build ----------------

__global__ void count_k(const int* __restrict__ ei, int* __restrict__ cnt, int E) {
    int e = blockIdx.x * 256 + threadIdx.x;
    if (e < E) atomicAdd(&cnt[ei[E + e]], 1);   // dst row of edge_index
}

__global__ __launch_bounds__(1024) void reduce_k(const int* __restrict__ cnt,
                                                 int* __restrict__ bsum, int N) {
    __shared__ int s[1024];
    int i = blockIdx.x * 1024 + threadIdx.x;
    int v = (i < N) ? cnt[i] : 0;
    s[threadIdx.x] = v;
    __syncthreads();
    for (int o = 512; o; o >>= 1) {
        if (threadIdx.x < o) s[threadIdx.x] += s[threadIdx.x + o];
        __syncthreads();
    }
    if (threadIdx.x == 0) bsum[blockIdx.x] = s[0];
}

__global__ __launch_bounds__(256) void scantop_k(const int* __restrict__ bsum,
                                                 int* __restrict__ boff, int NB) {
    __shared__ int s[256];
    int v = (threadIdx.x < NB) ? bsum[threadIdx.x] : 0;
    s[threadIdx.x] = v;
    __syncthreads();
    for (int o = 1; o < 256; o <<= 1) {
        int t = (threadIdx.x >= o) ? s[threadIdx.x - o] : 0;
        __syncthreads();
        s[threadIdx.x] += t;
        __syncthreads();
    }
    if (threadIdx.x < NB) boff[threadIdx.x] = s[threadIdx.x] - v;  // exclusive
}

__global__ __launch_bounds__(1024) void scanblk_k(const int* __restrict__ cnt,
                                                  const int* __restrict__ boff,
                                                  int* __restrict__ rowoff,
                                                  int* __restrict__ cursor,
                                                  float* __restrict__ inv, int N) {
    __shared__ int s[1024];
    int i = blockIdx.x * 1024 + threadIdx.x;
    int v = (i < N) ? cnt[i] : 0;
    s[threadIdx.x] = v;
    __syncthreads();
    for (int o = 1; o < 1024; o <<= 1) {
        int t = (threadIdx.x >= o) ? s[threadIdx.x - o] : 0;
        __syncthreads();
        s[threadIdx.x] += t;
        __syncthreads();
    }
    int ex = s[threadIdx.x] - v + boff[blockIdx.x];
    if (i < N) {
        rowoff[i] = ex;
        cursor[i] = ex;
        inv[i] = 1.0f / (float)max(v, 1);
        if (i == N - 1) rowoff[N] = ex + v;   // == E
    }
}

// XCD-partitioned fill: block group (blockIdx&7) handles dst range (dst>>13)&7.
// Every edge is scanned by all 8 groups, processed by exactly one -> correct
// regardless of actual block->XCD mapping; write combining in local L2 is the
// perf win (col positions for one dst-range form a contiguous window).
__global__ __launch_bounds__(256) void fill2_k(const int* __restrict__ ei,
                                               int* __restrict__ cursor,
                                               int* __restrict__ col, int E) {
    int xcd = blockIdx.x & 7;
    int nch = gridDim.x >> 3;
    for (int e = (blockIdx.x >> 3) * 256 + threadIdx.x; e < E; e += nch * 256) {
        int dst = ei[E + e];
        int src = ei[e];
        if (((dst >> 13) & 7) == xcd) {
            int pos = atomicAdd(&cursor[dst], 1);
            col[pos] = src;
        }
    }
}

// ---------------- dtype prep ----------------

__global__ void cvt_x_k(const float* __restrict__ x, unsigned short* __restrict__ xb,
                        int total4) {
    int i = blockIdx.x * 256 + threadIdx.x;
    if (i < total4) {
        float4 v = ((const float4*)x)[i];
        ushort4 p;
        p.x = f2bf(v.x); p.y = f2bf(v.y); p.z = f2bf(v.z); p.w = f2bf(v.w);
        ((ushort4*)xb)[i] = p;
    }
}

// W [128][128] f32 row-major -> bf16 B-fragment layout for mfma_f32_16x16x32_bf16
__global__ void cvt_w_k(const float* __restrict__ W0, const float* __restrict__ W1,
                        const float* __restrict__ W2, const float* __restrict__ W3,
                        unsigned short* __restrict__ wsz) {
    int idx = blockIdx.x * 256 + threadIdx.x;
    if (idx >= 4 * 16384) return;
    int m = idx >> 14, r = idx & 16383;
    const float* W = (m == 0) ? W0 : (m == 1) ? W1 : (m == 2) ? W2 : W3;
    int k = r >> 7, n = r & 127;
    int t = k >> 5, kg = (k >> 3) & 3, j = k & 7;
    int c = n >> 4, ln = n & 15;
    int dst = (((t * 8 + c) * 64) + kg * 16 + ln) * 8 + j;
    wsz[m * 16384 + dst] = f2bf(W[r]);
}

// ---------------- aggregation: wave per node, bf16 gather ----------------

__global__ __launch_bounds__(256) void agg_bf16(const unsigned short* __restrict__ h,
                                                const int* __restrict__ rowoff,
                                                const int* __restrict__ col,
                                                const float* __restrict__ inv,
                                                unsigned short* __restrict__ mean, int N) {
    int lane = threadIdx.x & 63;
    int n = blockIdx.x * 4 + (threadIdx.x >> 6);
    if (n >= N) return;
    int beg = rowoff[n], end = rowoff[n + 1];
    float a0 = 0.f, a1 = 0.f;
    for (int j0 = beg; j0 < end; j0 += 64) {
        int m = min(end - j0, 64);
        int src0 = (lane < m) ? col[j0 + lane] : 0;
#pragma unroll 4
        for (int jj = 0; jj < m; jj++) {
            int s = __shfl(src0, jj);
            unsigned int v = *(const unsigned int*)(h + (size_t)s * 128 + lane * 2);
            a0 += fmaxf(bf2f((unsigned short)(v & 0xFFFFu)), 0.f);
            a1 += fmaxf(bf2f((unsigned short)(v >> 16)), 0.f);
        }
    }
    float iv = inv[n];
    a0 *= iv; a1 *= iv;
    ushort2 p; p.x = f2bf(a0); p.y = f2bf(a1);
    *(ushort2*)(mean + (size_t)n * 128 + lane * 2) = p;
}

// ---------------- fused GEMM: out = A@Wa + Z@Wb + bias (opt relu) ----------------

template <bool RELU, bool OUT_BF16>
__global__ __launch_bounds__(256) void gemm_fused(const unsigned short* __restrict__ A,
                                                  const unsigned short* __restrict__ Z,
                                                  const unsigned short* __restrict__ wsz,
                                                  const float* __restrict__ bias,
                                                  float* __restrict__ outF,
                                                  unsigned short* __restrict__ outB,
                                                  int M, int NT) {
    __shared__ unsigned short smem[32768];   // 64 KB: [0]=Wa frags, [16384]=Wb frags
    {
        const int4* src = (const int4*)wsz;
        int4* dst = (int4*)smem;
        for (int i = threadIdx.x; i < 4096; i += 256) dst[i] = src[i];
    }
    __syncthreads();

    int lane = threadIdx.x & 63;
    int wv = threadIdx.x >> 6;
    int r16 = lane & 15, kg = lane >> 4;

    for (int rt = blockIdx.x * 4 + wv; rt < NT; rt += gridDim.x * 4) {
        int rbase = rt * 16;
        int row = rbase + r16;
        short8 af[4], zf[4];
        if (row < M) {
            const short8* ap = (const short8*)(A + (size_t)row * 128);
            const short8* zp = (const short8*)(Z + (size_t)row * 128);
#pragma unroll
            for (int t = 0; t < 4; t++) { af[t] = ap[t * 4 + kg]; zf[t] = zp[t * 4 + kg]; }
        } else {
            short8 zr = {0, 0, 0, 0, 0, 0, 0, 0};
#pragma unroll
            for (int t = 0; t < 4; t++) { af[t] = zr; zf[t] = zr; }
        }
#pragma unroll
        for (int c = 0; c < 8; c++) {
            float bv = bias[c * 16 + r16];
            f32x4 acc = {bv, bv, bv, bv};
#pragma unroll
            for (int t = 0; t < 4; t++) {
                short8 wa = *(const short8*)(smem + ((t * 8 + c) * 64 + lane) * 8);
                acc = __builtin_amdgcn_mfma_f32_16x16x32_bf16(af[t], wa, acc, 0, 0, 0);
            }
#pragma unroll
            for (int t = 0; t < 4; t++) {
                short8 wb = *(const short8*)(smem + 16384 + ((t * 8 + c) * 64 + lane) * 8);
                acc = __builtin_amdgcn_mfma_f32_16x16x32_bf16(zf[t], wb, acc, 0, 0, 0);
            }
#pragma unroll
            for (int r = 0; r < 4; r++) {
                int orow = rbase + kg * 4 + r;   // C/D: row=(lane>>4)*4+reg, col=lane&15
                if (orow < M) {
                    float v = acc[r];
                    if (RELU) v = fmaxf(v, 0.f);
                    if (OUT_BF16)
                        outB[(size_t)orow * 128 + c * 16 + r16] = f2bf(v);
                    else
                        outF[(size_t)orow * 128 + c * 16 + r16] = v;
                }
            }
        }
    }
}

// ---------------- launch ----------------

extern "C" void kernel_launch(void* const* d_in, const int* in_sizes, int n_in,
                              void* d_out, int out_size, void* d_ws, size_t ws_size,
                              hipStream_t stream) {
    const float* x   = (const float*)d_in[0];
    const int*   ei  = (const int*)d_in[1];
    const float* Wl1 = (const float*)d_in[2];
    const float* bl1 = (const float*)d_in[3];
    const float* Wr1 = (const float*)d_in[4];
    const float* Wl2 = (const float*)d_in[5];
    const float* bl2 = (const float*)d_in[6];
    const float* Wr2 = (const float*)d_in[7];

    int N = in_sizes[0] / 128;
    int E = in_sizes[1] / 2;

    char* ws = (char*)d_ws;
    size_t off = 0;
    auto alloc = [&](size_t bytes) -> char* {
        char* p = ws + off;
        off += (bytes + 255) & ~(size_t)255;
        return p;
    };
    int*   cnt    = (int*)alloc((size_t)N * 4);
    int*   rowoff = (int*)alloc((size_t)(N + 1) * 4);
    int*   cursor = (int*)alloc((size_t)N * 4);
    float* inv    = (float*)alloc((size_t)N * 4);
    int*   bsum   = (int*)alloc(256 * 4);
    int*   boff   = (int*)alloc(256 * 4);
    int*   col    = (int*)alloc((size_t)E * 4);
    unsigned short* xb    = (unsigned short*)alloc((size_t)N * 128 * 2);
    unsigned short* meanB = (unsigned short*)alloc((size_t)N * 128 * 2);
    unsigned short* hb    = (unsigned short*)alloc((size_t)N * 128 * 2);
    unsigned short* wsz   = (unsigned short*)alloc(4 * 16384 * 2);

    hipMemsetAsync(cnt, 0, (size_t)N * 4, stream);

    int NB = (N + 1023) / 1024;
    count_k<<<(E + 255) / 256, 256, 0, stream>>>(ei, cnt, E);
    reduce_k<<<NB, 1024, 0, stream>>>(cnt, bsum, N);
    scantop_k<<<1, 256, 0, stream>>>(bsum, boff, NB);
    scanblk_k<<<NB, 1024, 0, stream>>>(cnt, boff, rowoff, cursor, inv, N);
    fill2_k<<<1024, 256, 0, stream>>>(ei, cursor, col, E);

    cvt_x_k<<<(N * 128 / 4 + 255) / 256, 256, 0, stream>>>(x, xb, N * 128 / 4);
    cvt_w_k<<<(4 * 16384 + 255) / 256, 256, 0, stream>>>(Wl1, Wr1, Wl2, Wr2, wsz);

    int NT = (N + 15) / 16;
    // layer 1 (bf16 gather from xb)
    agg_bf16<<<(N + 3) / 4, 256, 0, stream>>>(xb, rowoff, col, inv, meanB, N);
    gemm_fused<true, true><<<512, 256, 0, stream>>>(meanB, xb, wsz, bl1, nullptr, hb, N, NT);
    // layer 2
    agg_bf16<<<(N + 3) / 4, 256, 0, stream>>>(hb, rowoff, col, inv, meanB, N);
    gemm_fused<false, false><<<512, 256, 0, stream>>>(meanB, hb, wsz + 32768, bl2,
                                                      (float*)d_out, nullptr, N, NT);
}

// Round 3
// 443.288 us; speedup vs baseline: 1.3752x; 1.1946x over previous
//
#include <hip/hip_runtime.h>

typedef short short8 __attribute__((ext_vector_type(8)));
typedef unsigned short ushort8 __attribute__((ext_vector_type(8)));
typedef float f32x4 __attribute__((ext_vector_type(4)));

__device__ __forceinline__ unsigned short f2bf(float f) {
    unsigned int u = __float_as_uint(f);
    u += 0x7FFFu + ((u >> 16) & 1u);   // RNE
    return (unsigned short)(u >> 16);
}
__device__ __forceinline__ float bf2f(unsigned short s) {
    return __uint_as_float(((unsigned int)s) << 16);
}

// ---------------- CSR build ----------------

// XCD-partitioned count: block group (blockIdx&7) only touches dst range
// ((dst>>13)&7) -> atomics stay in one XCD's L2 (correct under any mapping).
__global__ __launch_bounds__(256) void count2_k(const int* __restrict__ ei,
                                                int* __restrict__ cnt, int E) {
    int xcd = blockIdx.x & 7;
    int nch = gridDim.x >> 3;
    for (int e = (blockIdx.x >> 3) * 256 + threadIdx.x; e < E; e += nch * 256) {
        int dst = ei[E + e];
        if (((dst >> 13) & 7) == xcd) atomicAdd(&cnt[dst], 1);
    }
}

__global__ __launch_bounds__(1024) void reduce_k(const int* __restrict__ cnt,
                                                 int* __restrict__ bsum, int N) {
    __shared__ int s[1024];
    int i = blockIdx.x * 1024 + threadIdx.x;
    int v = (i < N) ? cnt[i] : 0;
    s[threadIdx.x] = v;
    __syncthreads();
    for (int o = 512; o; o >>= 1) {
        if (threadIdx.x < o) s[threadIdx.x] += s[threadIdx.x + o];
        __syncthreads();
    }
    if (threadIdx.x == 0) bsum[blockIdx.x] = s[0];
}

__global__ __launch_bounds__(256) void scantop_k(const int* __restrict__ bsum,
                                                 int* __restrict__ boff, int NB) {
    __shared__ int s[256];
    int v = (threadIdx.x < NB) ? bsum[threadIdx.x] : 0;
    s[threadIdx.x] = v;
    __syncthreads();
    for (int o = 1; o < 256; o <<= 1) {
        int t = (threadIdx.x >= o) ? s[threadIdx.x - o] : 0;
        __syncthreads();
        s[threadIdx.x] += t;
        __syncthreads();
    }
    if (threadIdx.x < NB) boff[threadIdx.x] = s[threadIdx.x] - v;  // exclusive
}

__global__ __launch_bounds__(1024) void scanblk_k(const int* __restrict__ cnt,
                                                  const int* __restrict__ boff,
                                                  int* __restrict__ rowoff,
                                                  int* __restrict__ cursor,
                                                  float* __restrict__ inv, int N) {
    __shared__ int s[1024];
    int i = blockIdx.x * 1024 + threadIdx.x;
    int v = (i < N) ? cnt[i] : 0;
    s[threadIdx.x] = v;
    __syncthreads();
    for (int o = 1; o < 1024; o <<= 1) {
        int t = (threadIdx.x >= o) ? s[threadIdx.x - o] : 0;
        __syncthreads();
        s[threadIdx.x] += t;
        __syncthreads();
    }
    int ex = s[threadIdx.x] - v + boff[blockIdx.x];
    if (i < N) {
        rowoff[i] = ex;
        cursor[i] = ex;
        inv[i] = 1.0f / (float)max(v, 1);
        if (i == N - 1) rowoff[N] = ex + v;   // == E
    }
}

__global__ __launch_bounds__(256) void fill2_k(const int* __restrict__ ei,
                                               int* __restrict__ cursor,
                                               int* __restrict__ col, int E) {
    int xcd = blockIdx.x & 7;
    int nch = gridDim.x >> 3;
    for (int e = (blockIdx.x >> 3) * 256 + threadIdx.x; e < E; e += nch * 256) {
        int dst = ei[E + e];
        int src = ei[e];
        if (((dst >> 13) & 7) == xcd) {
            int pos = atomicAdd(&cursor[dst], 1);
            col[pos] = src;
        }
    }
}

// ---------------- dtype prep ----------------

// converts N rows f32->bf16; also zeroes pad row N (gather target for invalid slots)
__global__ void cvt_x_k(const float* __restrict__ x, unsigned short* __restrict__ xb,
                        int total4) {
    int i = blockIdx.x * 256 + threadIdx.x;
    if (i < total4) {
        float4 v = ((const float4*)x)[i];
        ushort4 p;
        p.x = f2bf(v.x); p.y = f2bf(v.y); p.z = f2bf(v.z); p.w = f2bf(v.w);
        ((ushort4*)xb)[i] = p;
    } else if (i < total4 + 32) {
        ushort4 z; z.x = 0; z.y = 0; z.z = 0; z.w = 0;
        ((ushort4*)xb)[i] = z;
    }
}

__global__ void zrow_k(unsigned int* __restrict__ p) {
    if (threadIdx.x < 64) p[threadIdx.x] = 0;   // 128 ushorts = 64 uints
}

// W [128][128] f32 row-major -> bf16 B-fragment layout for mfma_f32_16x16x32_bf16
__global__ void cvt_w_k(const float* __restrict__ W0, const float* __restrict__ W1,
                        const float* __restrict__ W2, const float* __restrict__ W3,
                        unsigned short* __restrict__ wsz) {
    int idx = blockIdx.x * 256 + threadIdx.x;
    if (idx >= 4 * 16384) return;
    int m = idx >> 14, r = idx & 16383;
    const float* W = (m == 0) ? W0 : (m == 1) ? W1 : (m == 2) ? W2 : W3;
    int k = r >> 7, n = r & 127;
    int t = k >> 5, kg = (k >> 3) & 3, j = k & 7;
    int c = n >> 4, ln = n & 15;
    int dst = (((t * 8 + c) * 64) + kg * 16 + ln) * 8 + j;
    wsz[m * 16384 + dst] = f2bf(W[r]);
}

// ---------------- aggregation: wave per node, 4 edges in flight ----------------
// lane = (g, l16), g = lane>>4. Group g handles edges beg + 4*jj + g; lane loads
// 16B (8 ch) of the src row -> one load instruction fetches 4 rows (1KB).
// Invalid edge slots gather pad row N (zeros). Tail: shfl_xor(16,32) reduce.

__global__ __launch_bounds__(256) void agg_bf16(const unsigned short* __restrict__ h,
                                                const int* __restrict__ rowoff,
                                                const int* __restrict__ col,
                                                const float* __restrict__ inv,
                                                unsigned short* __restrict__ mean,
                                                int N) {
    int lane = threadIdx.x & 63;
    int g = lane >> 4, l16 = lane & 15;
    int n = blockIdx.x * 4 + (threadIdx.x >> 6);
    if (n >= N) return;
    int beg = rowoff[n], end = rowoff[n + 1];
    float a[8];
#pragma unroll
    for (int i = 0; i < 8; i++) a[i] = 0.f;

    for (int j0 = beg; j0 < end; j0 += 64) {
        int m = min(end - j0, 64);
        int src0 = (lane < m) ? col[j0 + lane] : N;   // pad slots -> zero row
        int iters = (m + 3) >> 2;
#pragma unroll 2
        for (int jj = 0; jj < iters; jj++) {
            int o = jj * 4 + g;                        // 0..63 always valid lane idx
            int s = __shfl(src0, o);                   // == N when o >= m
            ushort8 v = *(const ushort8*)(h + (size_t)s * 128 + l16 * 8);
#pragma unroll
            for (int i = 0; i < 8; i++) a[i] += fmaxf(bf2f(v[i]), 0.f);
        }
    }
    // combine the 4 group partials (channels identical across g)
#pragma unroll
    for (int i = 0; i < 8; i++) {
        a[i] += __shfl_xor(a[i], 16);
        a[i] += __shfl_xor(a[i], 32);
    }
    if (g == 0) {
        float iv = inv[n];
        ushort8 p;
#pragma unroll
        for (int i = 0; i < 8; i++) p[i] = f2bf(a[i] * iv);
        *(ushort8*)(mean + (size_t)n * 128 + l16 * 8) = p;
    }
}

// ---------------- fused GEMM: out = A@Wa + Z@Wb + bias (opt relu) ----------------

template <bool RELU, bool OUT_BF16>
__global__ __launch_bounds__(256) void gemm_fused(const unsigned short* __restrict__ A,
                                                  const unsigned short* __restrict__ Z,
                                                  const unsigned short* __restrict__ wsz,
                                                  const float* __restrict__ bias,
                                                  float* __restrict__ outF,
                                                  unsigned short* __restrict__ outB,
                                                  int M, int NT) {
    __shared__ unsigned short smem[32768];   // 64 KB: [0]=Wa frags, [16384]=Wb frags
    {
        const int4* src = (const int4*)wsz;
        int4* dst = (int4*)smem;
        for (int i = threadIdx.x; i < 4096; i += 256) dst[i] = src[i];
    }
    __syncthreads();

    int lane = threadIdx.x & 63;
    int wv = threadIdx.x >> 6;
    int r16 = lane & 15, kg = lane >> 4;

    for (int rt = blockIdx.x * 4 + wv; rt < NT; rt += gridDim.x * 4) {
        int rbase = rt * 16;
        int row = rbase + r16;
        short8 af[4], zf[4];
        if (row < M) {
            const short8* ap = (const short8*)(A + (size_t)row * 128);
            const short8* zp = (const short8*)(Z + (size_t)row * 128);
#pragma unroll
            for (int t = 0; t < 4; t++) { af[t] = ap[t * 4 + kg]; zf[t] = zp[t * 4 + kg]; }
        } else {
            short8 zr = {0, 0, 0, 0, 0, 0, 0, 0};
#pragma unroll
            for (int t = 0; t < 4; t++) { af[t] = zr; zf[t] = zr; }
        }
#pragma unroll
        for (int c = 0; c < 8; c++) {
            float bv = bias[c * 16 + r16];
            f32x4 acc = {bv, bv, bv, bv};
#pragma unroll
            for (int t = 0; t < 4; t++) {
                short8 wa = *(const short8*)(smem + ((t * 8 + c) * 64 + lane) * 8);
                acc = __builtin_amdgcn_mfma_f32_16x16x32_bf16(af[t], wa, acc, 0, 0, 0);
            }
#pragma unroll
            for (int t = 0; t < 4; t++) {
                short8 wb = *(const short8*)(smem + 16384 + ((t * 8 + c) * 64 + lane) * 8);
                acc = __builtin_amdgcn_mfma_f32_16x16x32_bf16(zf[t], wb, acc, 0, 0, 0);
            }
#pragma unroll
            for (int r = 0; r < 4; r++) {
                int orow = rbase + kg * 4 + r;   // C/D: row=(lane>>4)*4+reg, col=lane&15
                if (orow < M) {
                    float v = acc[r];
                    if (RELU) v = fmaxf(v, 0.f);
                    if (OUT_BF16)
                        outB[(size_t)orow * 128 + c * 16 + r16] = f2bf(v);
                    else
                        outF[(size_t)orow * 128 + c * 16 + r16] = v;
                }
            }
        }
    }
}

// ---------------- launch ----------------

extern "C" void kernel_launch(void* const* d_in, const int* in_sizes, int n_in,
                              void* d_out, int out_size, void* d_ws, size_t ws_size,
                              hipStream_t stream) {
    const float* x   = (const float*)d_in[0];
    const int*   ei  = (const int*)d_in[1];
    const float* Wl1 = (const float*)d_in[2];
    const float* bl1 = (const float*)d_in[3];
    const float* Wr1 = (const float*)d_in[4];
    const float* Wl2 = (const float*)d_in[5];
    const float* bl2 = (const float*)d_in[6];
    const float* Wr2 = (const float*)d_in[7];

    int N = in_sizes[0] / 128;
    int E = in_sizes[1] / 2;

    char* ws = (char*)d_ws;
    size_t off = 0;
    auto alloc = [&](size_t bytes) -> char* {
        char* p = ws + off;
        off += (bytes + 255) & ~(size_t)255;
        return p;
    };
    int*   cnt    = (int*)alloc((size_t)N * 4);
    int*   rowoff = (int*)alloc((size_t)(N + 1) * 4);
    int*   cursor = (int*)alloc((size_t)N * 4);
    float* inv    = (float*)alloc((size_t)N * 4);
    int*   bsum   = (int*)alloc(256 * 4);
    int*   boff   = (int*)alloc(256 * 4);
    int*   col    = (int*)alloc((size_t)E * 4);
    unsigned short* xb    = (unsigned short*)alloc((size_t)(N + 1) * 128 * 2);
    unsigned short* meanB = (unsigned short*)alloc((size_t)N * 128 * 2);
    unsigned short* hb    = (unsigned short*)alloc((size_t)(N + 1) * 128 * 2);
    unsigned short* wsz   = (unsigned short*)alloc(4 * 16384 * 2);

    hipMemsetAsync(cnt, 0, (size_t)N * 4, stream);

    int NB = (N + 1023) / 1024;
    count2_k<<<1024, 256, 0, stream>>>(ei, cnt, E);
    reduce_k<<<NB, 1024, 0, stream>>>(cnt, bsum, N);
    scantop_k<<<1, 256, 0, stream>>>(bsum, boff, NB);
    scanblk_k<<<NB, 1024, 0, stream>>>(cnt, boff, rowoff, cursor, inv, N);
    fill2_k<<<1024, 256, 0, stream>>>(ei, cursor, col, E);

    int total4 = N * 32;   // N rows of 128 bf16 in ushort4 units
    cvt_x_k<<<(total4 + 32 + 255) / 256, 256, 0, stream>>>(x, xb, total4);
    zrow_k<<<1, 64, 0, stream>>>((unsigned int*)(hb + (size_t)N * 128));
    cvt_w_k<<<(4 * 16384 + 255) / 256, 256, 0, stream>>>(Wl1, Wr1, Wl2, Wr2, wsz);

    int NT = (N + 15) / 16;
    // layer 1 (bf16 gather from xb)
    agg_bf16<<<(N + 3) / 4, 256, 0, stream>>>(xb, rowoff, col, inv, meanB, N);
    gemm_fused<true, true><<<512, 256, 0, stream>>>(meanB, xb, wsz, bl1, nullptr, hb, N, NT);
    // layer 2
    agg_bf16<<<(N + 3) / 4, 256, 0, stream>>>(hb, rowoff, col, inv, meanB, N);
    gemm_fused<false, false><<<512, 256, 0, stream>>>(meanB, hb, wsz + 32768, bl2,
                                                      (float*)d_out, nullptr, N, NT);
}